// Round 15
// baseline (212.264 us; speedup 1.0000x reference)
//
#include <hip/hip_runtime.h>
#include <stdint.h>

// N=2048, M=128, D_IN=352, H1=512, D=256, OUT_C=13.  All device tensors FLOAT32.
// Round 15: DIAGNOSTIC ABLATION. Base = R13 (best: main 52.6us, total 86.3).
// R7-R13 all land 52-64us regardless of structure; model says 10-15us -> ablate.
// attn_v0_full -> d_out (correctness); v1..v4 -> ws scratch, DCE-guarded.
//   v1 noexp: p = t            (transcendental + MFMA->VALU chain cost)
//   v2 nob:   bv4 = 1          (BencT global gather cost)
//   v3 nolds: af = bfr         (LDS-read latency cost; same MFMA count)
//   v4 ph1:   phase1 only      (phase1 vs phase2 split)

typedef __attribute__((ext_vector_type(4))) float float4_t;
typedef __attribute__((ext_vector_type(4))) float f32x4;
typedef __attribute__((ext_vector_type(8))) short bf16x8;
typedef __attribute__((ext_vector_type(8))) unsigned short ushort8_t;
typedef unsigned short ushort_t;

__device__ __forceinline__ unsigned short f2b(float f) {
  union { float f; unsigned int i; } v; v.f = f;
  unsigned int x = v.i;
  return (unsigned short)((x + 0x7FFFu + ((x >> 16) & 1u)) >> 16);
}

template<int ISBF>
__device__ __forceinline__ ushort8_t ld8(const void* base, size_t idx) {
  if constexpr (ISBF) {
    return *(const ushort8_t*)((const ushort_t*)base + idx);
  } else {
    const float* p = (const float*)base + idx;
    float4_t v0 = *(const float4_t*)p;
    float4_t v1 = *(const float4_t*)(p + 4);
    ushort8_t u;
    #pragma unroll
    for (int e = 0; e < 4; ++e) { u[e] = f2b(v0[e]); u[4 + e] = f2b(v1[e]); }
    return u;
  }
}

// ---------- MFMA encoder (R13, unchanged) ----------
template<int XBF, int WBF, int OUT_BF16>
__global__ __launch_bounds__(256) void enc_mfma(
    const void* __restrict__ XA, const void* __restrict__ WA,
    const float* __restrict__ bA, const float* __restrict__ gA, const float* __restrict__ beA,
    void* __restrict__ YA,
    const void* __restrict__ XB, const void* __restrict__ WB,
    const float* __restrict__ bB, const float* __restrict__ gB, const float* __restrict__ beB,
    void* __restrict__ YB, float* __restrict__ YBT,
    int J, int K, int nbxA)
{
  __shared__ ushort_t Xs[2][32][40];
  __shared__ ushort_t Ws[2][32][40];
  const int bx = blockIdx.x, by = blockIdx.y;
  const void* X; const void* W;
  const float *bb, *gg, *bev; void* Y; int i0, isB;
  if (bx < nbxA) { X = XA; W = WA; bb = bA; gg = gA; bev = beA; Y = YA; i0 = bx * 32; isB = 0; }
  else           { X = XB; W = WB; bb = bB; gg = gB; bev = beB; Y = YB; i0 = (bx - nbxA) * 32; isB = 1; }
  const int j0 = by * 32;
  const int tid = threadIdx.x, w = tid >> 6, lane = tid & 63, lg = lane >> 4, lr = lane & 15;
  const int mt = w >> 1, ct = w & 1;
  const int row = tid >> 2, k8 = (tid & 3) * 8;

  f32x4 acc = f32x4{0.f, 0.f, 0.f, 0.f};

  ushort8_t sv = (row < 32) ? ld8<XBF>(X, (size_t)(i0 + row) * K + k8)
                            : ld8<WBF>(W, (size_t)(j0 + row - 32) * K + k8);
  for (int kt = 0; kt < K; kt += 32) {
    const int buf = (kt >> 5) & 1;
    if (row < 32) *(ushort8_t*)&Xs[buf][row][k8] = sv;
    else          *(ushort8_t*)&Ws[buf][row - 32][k8] = sv;
    __syncthreads();
    if (kt + 32 < K)
      sv = (row < 32) ? ld8<XBF>(X, (size_t)(i0 + row) * K + kt + 32 + k8)
                      : ld8<WBF>(W, (size_t)(j0 + row - 32) * K + kt + 32 + k8);
    bf16x8 af = *(const bf16x8*)&Xs[buf][mt * 16 + lr][lg * 8];
    bf16x8 bf_ = *(const bf16x8*)&Ws[buf][ct * 16 + lr][lg * 8];
    acc = __builtin_amdgcn_mfma_f32_16x16x32_bf16(af, bf_, acc, 0, 0, 0);
  }
  const int c = j0 + ct * 16 + lr;
  const float g = gg[c], bv = bb[c], ev = bev[c];
  #pragma unroll
  for (int r = 0; r < 4; ++r) {
    const int rowo = i0 + mt * 16 + 4 * lg + r;
    float t = fmaxf(g * (acc[r] + bv) + ev, 0.f);
    if (OUT_BF16) ((ushort_t*)Y)[(size_t)rowo * J + c] = f2b(t);
    else {
      ((float*)Y)[(size_t)rowo * J + c] = t;
      if (isB && YBT) YBT[(size_t)c * 128 + rowo] = t;
    }
  }
}

// ---------- proj (R13, unchanged) ----------
__global__ __launch_bounds__(256) void proj32(
    const float* __restrict__ Aenc, const float* __restrict__ Benc,
    const float* __restrict__ mw1, const float* __restrict__ mb1,
    const float* __restrict__ mg1, const float* __restrict__ mbe1,
    float* __restrict__ PA2, float* __restrict__ PB2, int nbxA,
    const float* __restrict__ mw2, const float* __restrict__ mw3,
    ushort_t* __restrict__ mw2b, ushort_t* __restrict__ mw3b)
{
  __shared__ float ps[4][32];
  const int tid = threadIdx.x, bx = blockIdx.x;
  if (bx >= nbxA + 32) {
    const int g = (bx - nbxA - 32) * 256 + tid;
    const float* s; ushort_t* d; int j;
    if (g < 256) { s = mw2; d = mw2b; j = g; }
    else         { s = mw3; d = mw3b; j = g - 256; }
    float4_t v0 = *(const float4_t*)&s[(size_t)j * 8];
    float4_t v1 = *(const float4_t*)&s[(size_t)j * 8 + 4];
    ushort8_t u;
    #pragma unroll
    for (int e = 0; e < 4; ++e) { u[e] = f2b(v0[e]); u[4 + e] = f2b(v1[e]); }
    *(ushort8_t*)&d[(size_t)j * 8] = u;
    return;
  }
  const float* X; float* P; int n0, wb;
  if (bx < nbxA) { X = Aenc; P = PA2; n0 = bx * 4; wb = 1; }
  else           { X = Benc; P = PB2; n0 = (bx - nbxA) * 4; wb = 0; }
  const int k = tid & 31, r = (tid >> 5) & 3, half = tid >> 7;
  const int n = n0 + r;
  const float* xp = &X[(size_t)n * 256 + half * 128];
  const float* wp = &mw1[k * 256 + half * 128];
  float s = 0.f;
  #pragma unroll 8
  for (int q = 0; q < 128; q += 4) {
    float4_t xv = *(const float4_t*)&xp[q];
    float4_t wv = *(const float4_t*)&wp[q];
    #pragma unroll
    for (int e = 0; e < 4; ++e) s = fmaf(xv[e], wv[e], s);
  }
  if (half == 1) ps[r][k] = s;
  __syncthreads();
  if (half == 0) {
    s += ps[r][k];
    P[(size_t)n * 32 + k] = wb ? (mg1[k] * (s + mb1[k]) + mbe1[k]) : (mg1[k] * s);
  }
}

// ---------- main body (R13 structure), VAR-ablatable ----------
template<int VAR>
__device__ __forceinline__ void attn_body(
    const float* __restrict__ PA2, const float* __restrict__ PB2,
    const float* __restrict__ A, const float* __restrict__ BmT,
    const ushort_t* __restrict__ mw2b, const float* __restrict__ mb2,
    const float* __restrict__ mg2, const float* __restrict__ mbe2,
    const ushort_t* __restrict__ mw3b, const float* __restrict__ mb3,
    const float* __restrict__ mg3, const float* __restrict__ mbe3,
    const float* __restrict__ fcw, const float* __restrict__ fcb,
    float* __restrict__ outp, char* smem)
{
  const int tid = threadIdx.x;
  const int w = tid >> 6, lane = tid & 63, lg = lane >> 4, lr = lane & 15;
  const int n = blockIdx.x * 4 + w;
  ushort_t* h2s = (ushort_t*)(smem + w * 19456);
  float* attL   = (float*)(smem + w * 19456 + 18432);
  const float LOG2E = 1.4426950408889634f;

  // ---- phase1 ----
  {
    bf16x8 b1[4];
    float g2h[4], b2h[4], e2h[4];
    #pragma unroll
    for (int jt = 0; jt < 4; ++jt) {
      b1[jt] = *(const bf16x8*)&mw2b[(jt * 16 + lr) * 32 + lg * 8];
      const int j = jt * 16 + lr;
      g2h[jt] = mg2[j]; b2h[jt] = mb2[j]; e2h[jt] = mbe2[j];
    }
    const float* pa = &PA2[(size_t)n * 32 + lg * 8];
    float4_t pa0 = *(const float4_t*)pa;
    float4_t pa1 = *(const float4_t*)(pa + 4);
    #pragma unroll
    for (int mt = 0; mt < 8; ++mt) {
      const int m = mt * 16 + lr;
      const float* pb = &PB2[(size_t)m * 32 + lg * 8];
      float4_t pb0 = *(const float4_t*)pb;
      float4_t pb1 = *(const float4_t*)(pb + 4);
      bf16x8 a1;
      #pragma unroll
      for (int e = 0; e < 4; ++e) {
        a1[e]     = (short)f2b(fmaxf(pa0[e] - pb0[e], 0.f));
        a1[4 + e] = (short)f2b(fmaxf(pa1[e] - pb1[e], 0.f));
      }
      f32x4 acc1[4];
      #pragma unroll
      for (int jt = 0; jt < 4; ++jt) acc1[jt] = f32x4{0.f, 0.f, 0.f, 0.f};
      #pragma unroll
      for (int jt = 0; jt < 4; ++jt)
        acc1[jt] = __builtin_amdgcn_mfma_f32_16x16x32_bf16(a1, b1[jt], acc1[jt], 0, 0, 0);
      #pragma unroll
      for (int jt = 0; jt < 4; ++jt)
        #pragma unroll
        for (int r = 0; r < 4; ++r)
          h2s[(mt * 16 + 4 * lg + r) * 72 + jt * 16 + lr] =
              f2b(fmaxf(g2h[jt] * (acc1[jt][r] + b2h[jt]) + e2h[jt], 0.f));
    }
  }
  if constexpr (VAR == 4) {
    // phase1-only: read back one LDS element so the stores stay live
    if (lane == 0) outp[n] = (float)h2s[(size_t)(n & 63)];
    return;
  }

  // ---- phase2 + softmax: 16 ct-iterations ----
  #pragma unroll 2
  for (int ct = 0; ct < 16; ++ct) {
    const int c = ct * 16 + lr;
    bf16x8 bfr0 = *(const bf16x8*)&mw3b[(size_t)c * 64 + lg * 8];
    bf16x8 bfr1 = *(const bf16x8*)&mw3b[(size_t)c * 64 + 32 + lg * 8];
    f32x4 acc[8];
    #pragma unroll
    for (int mt = 0; mt < 8; ++mt) acc[mt] = f32x4{0.f, 0.f, 0.f, 0.f};
    #pragma unroll
    for (int mt = 0; mt < 8; ++mt) {
      bf16x8 af0, af1;
      if constexpr (VAR == 3) { af0 = bfr0; af1 = bfr1; }   // no LDS read
      else {
        af0 = *(const bf16x8*)&h2s[(mt * 16 + lr) * 72 + lg * 8];
        af1 = *(const bf16x8*)&h2s[(mt * 16 + lr) * 72 + 32 + lg * 8];
      }
      acc[mt] = __builtin_amdgcn_mfma_f32_16x16x32_bf16(af0, bfr0, acc[mt], 0, 0, 0);
      acc[mt] = __builtin_amdgcn_mfma_f32_16x16x32_bf16(af1, bfr1, acc[mt], 0, 0, 0);
    }
    const float g = mg3[c];
    const float gs = g * LOG2E;
    const float cs = (g * mb3[c] + mbe3[c]) * LOG2E;
    f32x4 sm4 = f32x4{0.f, 0.f, 0.f, 0.f};
    f32x4 wb4 = f32x4{0.f, 0.f, 0.f, 0.f};
    #pragma unroll
    for (int mt = 0; mt < 8; ++mt) {
      float4_t bv4;
      if constexpr (VAR == 2) bv4 = float4_t{1.f, 1.f, 1.f, 1.f};  // no B gather
      else bv4 = *(const float4_t*)&BmT[(size_t)c * 128 + mt * 16 + 4 * lg];
      #pragma unroll
      for (int r = 0; r < 4; ++r) {
        float t = fmaf(gs, acc[mt][r], cs);
        float p;
        if constexpr (VAR == 1) p = t;                              // no exp chain
        else p = __builtin_amdgcn_exp2f(__builtin_amdgcn_fmed3f(t, 0.f, 80.f));
        sm4[r] += p;
        wb4[r] = fmaf(p, bv4[r], wb4[r]);
      }
    }
    float sm = (sm4[0] + sm4[1]) + (sm4[2] + sm4[3]);
    float wb = (wb4[0] + wb4[1]) + (wb4[2] + wb4[3]);
    sm += __shfl_xor(sm, 16, 64);  wb += __shfl_xor(wb, 16, 64);
    sm += __shfl_xor(sm, 32, 64);  wb += __shfl_xor(wb, 32, 64);
    if (lg == 0)
      attL[c] = A[(size_t)n * 256 + c] - wb / (sm == 0.f ? 1.f : sm);
  }

  // ---- fc (intra-wave) ----
  {
    float4_t av = *(const float4_t*)&attL[lane * 4];
    #pragma unroll
    for (int o = 0; o < 13; ++o) {
      float4_t wv = *(const float4_t*)&fcw[(size_t)o * 256 + lane * 4];
      float s = av[0] * wv[0];
      s = fmaf(av[1], wv[1], s);
      s = fmaf(av[2], wv[2], s);
      s = fmaf(av[3], wv[3], s);
      #pragma unroll
      for (int st = 1; st <= 32; st <<= 1) s += __shfl_xor(s, st, 64);
      if (lane == 0) outp[(size_t)n * 13 + o] = s + fcb[o];
    }
  }
}

#define ATTN_ARGS  const float* __restrict__ PA2, const float* __restrict__ PB2, \
    const float* __restrict__ A, const float* __restrict__ BmT, \
    const ushort_t* __restrict__ mw2b, const float* __restrict__ mb2, \
    const float* __restrict__ mg2, const float* __restrict__ mbe2, \
    const ushort_t* __restrict__ mw3b, const float* __restrict__ mb3, \
    const float* __restrict__ mg3, const float* __restrict__ mbe3, \
    const float* __restrict__ fcw, const float* __restrict__ fcb, \
    float* __restrict__ outp
#define ATTN_PASS  PA2, PB2, A, BmT, mw2b, mb2, mg2, mbe2, mw3b, mb3, mg3, mbe3, fcw, fcb, outp, smem

__global__ __launch_bounds__(256, 2) void attn_v0_full (ATTN_ARGS) { __shared__ __align__(16) char smem[77824]; attn_body<0>(ATTN_PASS); }
__global__ __launch_bounds__(256, 2) void attn_v1_noexp(ATTN_ARGS) { __shared__ __align__(16) char smem[77824]; attn_body<1>(ATTN_PASS); }
__global__ __launch_bounds__(256, 2) void attn_v2_nob  (ATTN_ARGS) { __shared__ __align__(16) char smem[77824]; attn_body<2>(ATTN_PASS); }
__global__ __launch_bounds__(256, 2) void attn_v3_nolds(ATTN_ARGS) { __shared__ __align__(16) char smem[77824]; attn_body<3>(ATTN_PASS); }
__global__ __launch_bounds__(256, 2) void attn_v4_ph1  (ATTN_ARGS) { __shared__ __align__(16) char smem[77824]; attn_body<4>(ATTN_PASS); }

extern "C" void kernel_launch(void* const* d_in, const int* in_sizes, int n_in,
                              void* d_out, int out_size, void* d_ws, size_t ws_size,
                              hipStream_t stream)
{
  const float* ext = (const float*)d_in[0];
  const float* lab = (const float*)d_in[1];
  const float* w1a = (const float*)d_in[2];
  const float* b1a = (const float*)d_in[3];
  const float* g1a = (const float*)d_in[4];
  const float* be1a= (const float*)d_in[5];
  const float* w1b = (const float*)d_in[6];
  const float* b1b = (const float*)d_in[7];
  const float* g1b = (const float*)d_in[8];
  const float* be1b= (const float*)d_in[9];
  const float* w2a = (const float*)d_in[10];
  const float* b2a = (const float*)d_in[11];
  const float* g2a = (const float*)d_in[12];
  const float* be2a= (const float*)d_in[13];
  const float* w2b = (const float*)d_in[14];
  const float* b2b = (const float*)d_in[15];
  const float* g2b = (const float*)d_in[16];
  const float* be2b= (const float*)d_in[17];
  const float* mw1 = (const float*)d_in[18];
  const float* mb1 = (const float*)d_in[19];
  const float* mg1 = (const float*)d_in[20];
  const float* mbe1= (const float*)d_in[21];
  const float* mw2 = (const float*)d_in[22];
  const float* mb2 = (const float*)d_in[23];
  const float* mg2 = (const float*)d_in[24];
  const float* mbe2= (const float*)d_in[25];
  const float* mw3 = (const float*)d_in[26];
  const float* mb3 = (const float*)d_in[27];
  const float* mg3 = (const float*)d_in[28];
  const float* mbe3= (const float*)d_in[29];
  const float* fcw = (const float*)d_in[30];
  const float* fcb = (const float*)d_in[31];

  char* ws = (char*)d_ws;
  ushort_t* Y1ab = (ushort_t*)(ws);                       // [0,2M) bf16 (dead after enc2)
  float*    PA2  = (float*)(ws);                          // [0,256K) written by proj
  float*    PB2  = (float*)(ws + 262144);                 // [256K,272K)
  float*    Aenc = (float*)(ws + (2u << 20));             // [2M,4M)
  char* b5 = ws + (4u << 20);
  ushort_t* mw2b = (ushort_t*)(b5);                       // 64x32 bf16
  ushort_t* mw3b = (ushort_t*)(b5 + 4096);                // 256x64 bf16
  ushort_t* Y1bb = (ushort_t*)(b5 + 36864);               // 128x512 bf16
  float*    Benc = (float*)(b5 + 167936);                 // 128x256 f32
  float*    BencT= (float*)(b5 + 299008);                 // 256x128 f32
  float*    vscr = (float*)(ws + (5u << 20));             // variant scratch (128KB)

  enc_mfma<0, 0, 1><<<dim3(68, 16), 256, 0, stream>>>(
      (const void*)ext, (const void*)w1a, b1a, g1a, be1a, (void*)Y1ab,
      (const void*)lab, (const void*)w2a, b2a, g2a, be2a, (void*)Y1bb,
      (float*)nullptr, 512, 352, 64);
  enc_mfma<1, 0, 0><<<dim3(68, 8), 256, 0, stream>>>(
      (const void*)Y1ab, (const void*)w1b, b1b, g1b, be1b, (void*)Aenc,
      (const void*)Y1bb, (const void*)w2b, b2b, g2b, be2b, (void*)Benc,
      BencT, 256, 512, 64);
  proj32<<<553, 256, 0, stream>>>(Aenc, Benc, mw1, mb1, mg1, mbe1, PA2, PB2, 512,
                                  mw2, mw3, mw2b, mw3b);
  attn_v0_full<<<512, 256, 0, stream>>>(PA2, PB2, Aenc, BencT,
                                        mw2b, mb2, mg2, mbe2, mw3b, mb3, mg3, mbe3,
                                        fcw, fcb, (float*)d_out);
  attn_v1_noexp<<<512, 256, 0, stream>>>(PA2, PB2, Aenc, BencT,
                                         mw2b, mb2, mg2, mbe2, mw3b, mb3, mg3, mbe3,
                                         fcw, fcb, vscr);
  attn_v2_nob<<<512, 256, 0, stream>>>(PA2, PB2, Aenc, BencT,
                                       mw2b, mb2, mg2, mbe2, mw3b, mb3, mg3, mbe3,
                                       fcw, fcb, vscr);
  attn_v3_nolds<<<512, 256, 0, stream>>>(PA2, PB2, Aenc, BencT,
                                         mw2b, mb2, mg2, mbe2, mw3b, mb3, mg3, mbe3,
                                         fcw, fcb, vscr);
  attn_v4_ph1<<<512, 256, 0, stream>>>(PA2, PB2, Aenc, BencT,
                                       mw2b, mb2, mg2, mbe2, mw3b, mb3, mg3, mbe3,
                                       fcw, fcb, vscr);
}

// Round 16
// 86.922 us; speedup vs baseline: 2.4420x; 2.4420x over previous
//
#include <hip/hip_runtime.h>
#include <stdint.h>

// N=2048, M=128, D_IN=352, H1=512, D=256, OUT_C=13.  All device tensors FLOAT32.
// Round 16: ILP round.  R15 ablation: no dominant class (each ~13-18us of a 52us
// wall); whole grid co-resident -> per-n chain latency IS the wall; VALUBusy 28% /
// MfmaUtil 6.6% match "per-ct 2.4k-cyc chain, 700cyc issue".  VGPR was 88 with a
// 256 budget (LDS caps occupancy at 2 waves/SIMD regardless) -> spend registers:
// hoist Av/gs/cs (48 loads) + phase1 PB2 (16 float4), fully unroll the ct loop so
// the scheduler pipelines iterations.  Encoders/proj unchanged (R13).

typedef __attribute__((ext_vector_type(4))) float float4_t;
typedef __attribute__((ext_vector_type(4))) float f32x4;
typedef __attribute__((ext_vector_type(8))) short bf16x8;
typedef __attribute__((ext_vector_type(8))) unsigned short ushort8_t;
typedef unsigned short ushort_t;

__device__ __forceinline__ unsigned short f2b(float f) {
  union { float f; unsigned int i; } v; v.f = f;
  unsigned int x = v.i;
  return (unsigned short)((x + 0x7FFFu + ((x >> 16) & 1u)) >> 16);
}

template<int ISBF>
__device__ __forceinline__ ushort8_t ld8(const void* base, size_t idx) {
  if constexpr (ISBF) {
    return *(const ushort8_t*)((const ushort_t*)base + idx);
  } else {
    const float* p = (const float*)base + idx;
    float4_t v0 = *(const float4_t*)p;
    float4_t v1 = *(const float4_t*)(p + 4);
    ushort8_t u;
    #pragma unroll
    for (int e = 0; e < 4; ++e) { u[e] = f2b(v0[e]); u[4 + e] = f2b(v1[e]); }
    return u;
  }
}

// ---------- MFMA encoder (R13, unchanged) ----------
template<int XBF, int WBF, int OUT_BF16>
__global__ __launch_bounds__(256) void enc_mfma(
    const void* __restrict__ XA, const void* __restrict__ WA,
    const float* __restrict__ bA, const float* __restrict__ gA, const float* __restrict__ beA,
    void* __restrict__ YA,
    const void* __restrict__ XB, const void* __restrict__ WB,
    const float* __restrict__ bB, const float* __restrict__ gB, const float* __restrict__ beB,
    void* __restrict__ YB, float* __restrict__ YBT,
    int J, int K, int nbxA)
{
  __shared__ ushort_t Xs[2][32][40];
  __shared__ ushort_t Ws[2][32][40];
  const int bx = blockIdx.x, by = blockIdx.y;
  const void* X; const void* W;
  const float *bb, *gg, *bev; void* Y; int i0, isB;
  if (bx < nbxA) { X = XA; W = WA; bb = bA; gg = gA; bev = beA; Y = YA; i0 = bx * 32; isB = 0; }
  else           { X = XB; W = WB; bb = bB; gg = gB; bev = beB; Y = YB; i0 = (bx - nbxA) * 32; isB = 1; }
  const int j0 = by * 32;
  const int tid = threadIdx.x, w = tid >> 6, lane = tid & 63, lg = lane >> 4, lr = lane & 15;
  const int mt = w >> 1, ct = w & 1;
  const int row = tid >> 2, k8 = (tid & 3) * 8;

  f32x4 acc = f32x4{0.f, 0.f, 0.f, 0.f};

  ushort8_t sv = (row < 32) ? ld8<XBF>(X, (size_t)(i0 + row) * K + k8)
                            : ld8<WBF>(W, (size_t)(j0 + row - 32) * K + k8);
  for (int kt = 0; kt < K; kt += 32) {
    const int buf = (kt >> 5) & 1;
    if (row < 32) *(ushort8_t*)&Xs[buf][row][k8] = sv;
    else          *(ushort8_t*)&Ws[buf][row - 32][k8] = sv;
    __syncthreads();
    if (kt + 32 < K)
      sv = (row < 32) ? ld8<XBF>(X, (size_t)(i0 + row) * K + kt + 32 + k8)
                      : ld8<WBF>(W, (size_t)(j0 + row - 32) * K + kt + 32 + k8);
    bf16x8 af = *(const bf16x8*)&Xs[buf][mt * 16 + lr][lg * 8];
    bf16x8 bf_ = *(const bf16x8*)&Ws[buf][ct * 16 + lr][lg * 8];
    acc = __builtin_amdgcn_mfma_f32_16x16x32_bf16(af, bf_, acc, 0, 0, 0);
  }
  const int c = j0 + ct * 16 + lr;
  const float g = gg[c], bv = bb[c], ev = bev[c];
  #pragma unroll
  for (int r = 0; r < 4; ++r) {
    const int rowo = i0 + mt * 16 + 4 * lg + r;
    float t = fmaxf(g * (acc[r] + bv) + ev, 0.f);
    if (OUT_BF16) ((ushort_t*)Y)[(size_t)rowo * J + c] = f2b(t);
    else {
      ((float*)Y)[(size_t)rowo * J + c] = t;
      if (isB && YBT) YBT[(size_t)c * 128 + rowo] = t;
    }
  }
}

// ---------- proj (R13, unchanged) ----------
__global__ __launch_bounds__(256) void proj32(
    const float* __restrict__ Aenc, const float* __restrict__ Benc,
    const float* __restrict__ mw1, const float* __restrict__ mb1,
    const float* __restrict__ mg1, const float* __restrict__ mbe1,
    float* __restrict__ PA2, float* __restrict__ PB2, int nbxA,
    const float* __restrict__ mw2, const float* __restrict__ mw3,
    ushort_t* __restrict__ mw2b, ushort_t* __restrict__ mw3b)
{
  __shared__ float ps[4][32];
  const int tid = threadIdx.x, bx = blockIdx.x;
  if (bx >= nbxA + 32) {
    const int g = (bx - nbxA - 32) * 256 + tid;
    const float* s; ushort_t* d; int j;
    if (g < 256) { s = mw2; d = mw2b; j = g; }
    else         { s = mw3; d = mw3b; j = g - 256; }
    float4_t v0 = *(const float4_t*)&s[(size_t)j * 8];
    float4_t v1 = *(const float4_t*)&s[(size_t)j * 8 + 4];
    ushort8_t u;
    #pragma unroll
    for (int e = 0; e < 4; ++e) { u[e] = f2b(v0[e]); u[4 + e] = f2b(v1[e]); }
    *(ushort8_t*)&d[(size_t)j * 8] = u;
    return;
  }
  const float* X; float* P; int n0, wb;
  if (bx < nbxA) { X = Aenc; P = PA2; n0 = bx * 4; wb = 1; }
  else           { X = Benc; P = PB2; n0 = (bx - nbxA) * 4; wb = 0; }
  const int k = tid & 31, r = (tid >> 5) & 3, half = tid >> 7;
  const int n = n0 + r;
  const float* xp = &X[(size_t)n * 256 + half * 128];
  const float* wp = &mw1[k * 256 + half * 128];
  float s = 0.f;
  #pragma unroll 8
  for (int q = 0; q < 128; q += 4) {
    float4_t xv = *(const float4_t*)&xp[q];
    float4_t wv = *(const float4_t*)&wp[q];
    #pragma unroll
    for (int e = 0; e < 4; ++e) s = fmaf(xv[e], wv[e], s);
  }
  if (half == 1) ps[r][k] = s;
  __syncthreads();
  if (half == 0) {
    s += ps[r][k];
    P[(size_t)n * 32 + k] = wb ? (mg1[k] * (s + mb1[k]) + mbe1[k]) : (mg1[k] * s);
  }
}

// ---------- fused main kernel: one wave = one n, zero barriers, ILP-maximized ----------
// MFMA 16x16x32_bf16: A frag m=lane&15,k=(lane>>4)*8+e; B frag c=lane&15,same k;
// C/D col=lane&15,row=(lane>>4)*4+reg.
// Per-wave slab: h2[128][72] bf16 + att[256] f32 = 19456B; 4 waves/block = 77824B,
// 2 blocks/CU (8 waves, entire grid co-resident).  VGPR budget 256/wave: Av/gs/cs
// hoisted (48 loads overlap phase1), PB2 hoisted (16 float4), ct loop fully
// unrolled so the scheduler pipelines independent iterations.
__global__ __launch_bounds__(256, 2) void main_attn(
    const float* __restrict__ PA2, const float* __restrict__ PB2,
    const float* __restrict__ A, const float* __restrict__ BmT,
    const ushort_t* __restrict__ mw2b, const float* __restrict__ mb2,
    const float* __restrict__ mg2, const float* __restrict__ mbe2,
    const ushort_t* __restrict__ mw3b, const float* __restrict__ mb3,
    const float* __restrict__ mg3, const float* __restrict__ mbe3,
    const float* __restrict__ fcw, const float* __restrict__ fcb,
    float* __restrict__ outp)
{
  __shared__ __align__(16) char smem[77824];
  const int tid = threadIdx.x;
  const int w = tid >> 6, lane = tid & 63, lg = lane >> 4, lr = lane & 15;
  const int n = blockIdx.x * 4 + w;
  ushort_t* h2s = (ushort_t*)(smem + w * 19456);
  float* attL   = (float*)(smem + w * 19456 + 18432);
  const float LOG2E = 1.4426950408889634f;

  // ---- hoisted per-ct constants & tail loads (issue now, fill under phase1) ----
  float Av[16], gsv[16], csv[16];
  #pragma unroll
  for (int ct = 0; ct < 16; ++ct) {
    const int c = ct * 16 + lr;
    Av[ct] = A[(size_t)n * 256 + c];
    const float g = mg3[c];
    gsv[ct] = g * LOG2E;
    csv[ct] = (g * mb3[c] + mbe3[c]) * LOG2E;
  }

  // ---- phase1: h2[m][j] = relu(g2*(relu(PA2[n]-PB2[m]) @ mw2^T + b2) + be2) ----
  {
    bf16x8 b1[4];
    float g2h[4], b2h[4], e2h[4];
    #pragma unroll
    for (int jt = 0; jt < 4; ++jt) {
      b1[jt] = *(const bf16x8*)&mw2b[(jt * 16 + lr) * 32 + lg * 8];
      const int j = jt * 16 + lr;
      g2h[jt] = mg2[j]; b2h[jt] = mb2[j]; e2h[jt] = mbe2[j];
    }
    const float* pa = &PA2[(size_t)n * 32 + lg * 8];
    float4_t pa0 = *(const float4_t*)pa;
    float4_t pa1 = *(const float4_t*)(pa + 4);
    // hoist all PB2 loads: 8 mt x 2 float4 -> all L2 latencies overlap
    float4_t pbv0[8], pbv1[8];
    #pragma unroll
    for (int mt = 0; mt < 8; ++mt) {
      const float* pb = &PB2[(size_t)(mt * 16 + lr) * 32 + lg * 8];
      pbv0[mt] = *(const float4_t*)pb;
      pbv1[mt] = *(const float4_t*)(pb + 4);
    }
    #pragma unroll
    for (int mt = 0; mt < 8; ++mt) {
      bf16x8 a1;
      #pragma unroll
      for (int e = 0; e < 4; ++e) {
        a1[e]     = (short)f2b(fmaxf(pa0[e] - pbv0[mt][e], 0.f));
        a1[4 + e] = (short)f2b(fmaxf(pa1[e] - pbv1[mt][e], 0.f));
      }
      f32x4 acc1[4];
      #pragma unroll
      for (int jt = 0; jt < 4; ++jt) acc1[jt] = f32x4{0.f, 0.f, 0.f, 0.f};
      #pragma unroll
      for (int jt = 0; jt < 4; ++jt)
        acc1[jt] = __builtin_amdgcn_mfma_f32_16x16x32_bf16(a1, b1[jt], acc1[jt], 0, 0, 0);
      #pragma unroll
      for (int jt = 0; jt < 4; ++jt)
        #pragma unroll
        for (int r = 0; r < 4; ++r)
          h2s[(mt * 16 + 4 * lg + r) * 72 + jt * 16 + lr] =
              f2b(fmaxf(g2h[jt] * (acc1[jt][r] + b2h[jt]) + e2h[jt], 0.f));
    }
  }
  // intra-wave LDS ordering: compiler-inserted lgkmcnt; no barrier needed.

  // ---- phase2 + softmax: 16 ct-iterations, FULLY unrolled (scheduler pipelines) ----
  #pragma unroll
  for (int ct = 0; ct < 16; ++ct) {
    const int c = ct * 16 + lr;
    bf16x8 bfr0 = *(const bf16x8*)&mw3b[(size_t)c * 64 + lg * 8];
    bf16x8 bfr1 = *(const bf16x8*)&mw3b[(size_t)c * 64 + 32 + lg * 8];
    f32x4 acc[8];
    #pragma unroll
    for (int mt = 0; mt < 8; ++mt) acc[mt] = f32x4{0.f, 0.f, 0.f, 0.f};
    #pragma unroll
    for (int mt = 0; mt < 8; ++mt) {
      bf16x8 af0 = *(const bf16x8*)&h2s[(mt * 16 + lr) * 72 + lg * 8];
      acc[mt] = __builtin_amdgcn_mfma_f32_16x16x32_bf16(af0, bfr0, acc[mt], 0, 0, 0);
      bf16x8 af1 = *(const bf16x8*)&h2s[(mt * 16 + lr) * 72 + 32 + lg * 8];
      acc[mt] = __builtin_amdgcn_mfma_f32_16x16x32_bf16(af1, bfr1, acc[mt], 0, 0, 0);
    }
    f32x4 sm4 = f32x4{0.f, 0.f, 0.f, 0.f};
    f32x4 wb4 = f32x4{0.f, 0.f, 0.f, 0.f};
    #pragma unroll
    for (int mt = 0; mt < 8; ++mt) {
      float4_t bv4 = *(const float4_t*)&BmT[(size_t)c * 128 + mt * 16 + 4 * lg];
      #pragma unroll
      for (int r = 0; r < 4; ++r) {
        float t = fmaf(gsv[ct], acc[mt][r], csv[ct]);
        float p = __builtin_amdgcn_exp2f(__builtin_amdgcn_fmed3f(t, 0.f, 80.f));
        sm4[r] += p;
        wb4[r] = fmaf(p, bv4[r], wb4[r]);
      }
    }
    float sm = (sm4[0] + sm4[1]) + (sm4[2] + sm4[3]);
    float wb = (wb4[0] + wb4[1]) + (wb4[2] + wb4[3]);
    sm += __shfl_xor(sm, 16, 64);  wb += __shfl_xor(wb, 16, 64);
    sm += __shfl_xor(sm, 32, 64);  wb += __shfl_xor(wb, 32, 64);
    if (lg == 0)
      attL[c] = Av[ct] - wb / sm;
  }

  // ---- fc (intra-wave): lane covers c = lane*4..lane*4+3 ----
  {
    float4_t av = *(const float4_t*)&attL[lane * 4];
    #pragma unroll
    for (int o = 0; o < 13; ++o) {
      float4_t wv = *(const float4_t*)&fcw[(size_t)o * 256 + lane * 4];
      float s = av[0] * wv[0];
      s = fmaf(av[1], wv[1], s);
      s = fmaf(av[2], wv[2], s);
      s = fmaf(av[3], wv[3], s);
      #pragma unroll
      for (int st = 1; st <= 32; st <<= 1) s += __shfl_xor(s, st, 64);
      if (lane == 0) outp[(size_t)n * 13 + o] = s + fcb[o];
    }
  }
}

extern "C" void kernel_launch(void* const* d_in, const int* in_sizes, int n_in,
                              void* d_out, int out_size, void* d_ws, size_t ws_size,
                              hipStream_t stream)
{
  const float* ext = (const float*)d_in[0];
  const float* lab = (const float*)d_in[1];
  const float* w1a = (const float*)d_in[2];
  const float* b1a = (const float*)d_in[3];
  const float* g1a = (const float*)d_in[4];
  const float* be1a= (const float*)d_in[5];
  const float* w1b = (const float*)d_in[6];
  const float* b1b = (const float*)d_in[7];
  const float* g1b = (const float*)d_in[8];
  const float* be1b= (const float*)d_in[9];
  const float* w2a = (const float*)d_in[10];
  const float* b2a = (const float*)d_in[11];
  const float* g2a = (const float*)d_in[12];
  const float* be2a= (const float*)d_in[13];
  const float* w2b = (const float*)d_in[14];
  const float* b2b = (const float*)d_in[15];
  const float* g2b = (const float*)d_in[16];
  const float* be2b= (const float*)d_in[17];
  const float* mw1 = (const float*)d_in[18];
  const float* mb1 = (const float*)d_in[19];
  const float* mg1 = (const float*)d_in[20];
  const float* mbe1= (const float*)d_in[21];
  const float* mw2 = (const float*)d_in[22];
  const float* mb2 = (const float*)d_in[23];
  const float* mg2 = (const float*)d_in[24];
  const float* mbe2= (const float*)d_in[25];
  const float* mw3 = (const float*)d_in[26];
  const float* mb3 = (const float*)d_in[27];
  const float* mg3 = (const float*)d_in[28];
  const float* mbe3= (const float*)d_in[29];
  const float* fcw = (const float*)d_in[30];
  const float* fcb = (const float*)d_in[31];

  char* ws = (char*)d_ws;
  ushort_t* Y1ab = (ushort_t*)(ws);                       // [0,2M) bf16 (dead after enc2)
  float*    PA2  = (float*)(ws);                          // [0,256K) written by proj
  float*    PB2  = (float*)(ws + 262144);                 // [256K,272K)
  float*    Aenc = (float*)(ws + (2u << 20));             // [2M,4M)
  char* b5 = ws + (4u << 20);
  ushort_t* mw2b = (ushort_t*)(b5);                       // 64x32 bf16
  ushort_t* mw3b = (ushort_t*)(b5 + 4096);                // 256x64 bf16
  ushort_t* Y1bb = (ushort_t*)(b5 + 36864);               // 128x512 bf16
  float*    Benc = (float*)(b5 + 167936);                 // 128x256 f32
  float*    BencT= (float*)(b5 + 299008);                 // 256x128 f32

  enc_mfma<0, 0, 1><<<dim3(68, 16), 256, 0, stream>>>(
      (const void*)ext, (const void*)w1a, b1a, g1a, be1a, (void*)Y1ab,
      (const void*)lab, (const void*)w2a, b2a, g2a, be2a, (void*)Y1bb,
      (float*)nullptr, 512, 352, 64);
  enc_mfma<1, 0, 0><<<dim3(68, 8), 256, 0, stream>>>(
      (const void*)Y1ab, (const void*)w1b, b1b, g1b, be1b, (void*)Aenc,
      (const void*)Y1bb, (const void*)w2b, b2b, g2b, be2b, (void*)Benc,
      BencT, 256, 512, 64);
  proj32<<<553, 256, 0, stream>>>(Aenc, Benc, mw1, mb1, mg1, mbe1, PA2, PB2, 512,
                                  mw2, mw3, mw2b, mw3b);
  main_attn<<<512, 256, 0, stream>>>(PA2, PB2, Aenc, BencT,
                                     mw2b, mb2, mg2, mbe2, mw3b, mb3, mg3, mbe3,
                                     fcw, fcb, (float*)d_out);
}

// Round 17
// 86.090 us; speedup vs baseline: 2.4656x; 1.0097x over previous
//
#include <hip/hip_runtime.h>
#include <stdint.h>

// N=2048, M=128, D_IN=352, H1=512, D=256, OUT_C=13.  All device tensors FLOAT32.
// Round 17: A-fragment-resident phase2.  R16 showed ILP hoists were no-ops; cost
// model says LDS re-reads dominate (phase2 read h2 16x = 256 b128/wave).  The whole
// h2-as-A-frags is only 64 VGPR -> read ONCE (16 b128), keep in regs for all ct.
// Plus BencTb bf16 (halves L2 stream).  Everything else = R13/R16 skeleton.

typedef __attribute__((ext_vector_type(4))) float float4_t;
typedef __attribute__((ext_vector_type(4))) float f32x4;
typedef __attribute__((ext_vector_type(8))) short bf16x8;
typedef __attribute__((ext_vector_type(8))) unsigned short ushort8_t;
typedef __attribute__((ext_vector_type(4))) unsigned short ushort4_t;
typedef unsigned short ushort_t;

__device__ __forceinline__ float b2f(unsigned short u) {
  union { unsigned int i; float f; } v; v.i = ((unsigned int)u) << 16; return v.f;
}
__device__ __forceinline__ unsigned short f2b(float f) {
  union { float f; unsigned int i; } v; v.f = f;
  unsigned int x = v.i;
  return (unsigned short)((x + 0x7FFFu + ((x >> 16) & 1u)) >> 16);
}

template<int ISBF>
__device__ __forceinline__ ushort8_t ld8(const void* base, size_t idx) {
  if constexpr (ISBF) {
    return *(const ushort8_t*)((const ushort_t*)base + idx);
  } else {
    const float* p = (const float*)base + idx;
    float4_t v0 = *(const float4_t*)p;
    float4_t v1 = *(const float4_t*)(p + 4);
    ushort8_t u;
    #pragma unroll
    for (int e = 0; e < 4; ++e) { u[e] = f2b(v0[e]); u[4 + e] = f2b(v1[e]); }
    return u;
  }
}

// ---------- MFMA encoder (R13 structure); B-branch of f32-out stage also
// writes the bf16 transposed copy YBTb[c*128+row] ----------
template<int XBF, int WBF, int OUT_BF16>
__global__ __launch_bounds__(256) void enc_mfma(
    const void* __restrict__ XA, const void* __restrict__ WA,
    const float* __restrict__ bA, const float* __restrict__ gA, const float* __restrict__ beA,
    void* __restrict__ YA,
    const void* __restrict__ XB, const void* __restrict__ WB,
    const float* __restrict__ bB, const float* __restrict__ gB, const float* __restrict__ beB,
    void* __restrict__ YB, ushort_t* __restrict__ YBTb,
    int J, int K, int nbxA)
{
  __shared__ ushort_t Xs[2][32][40];
  __shared__ ushort_t Ws[2][32][40];
  const int bx = blockIdx.x, by = blockIdx.y;
  const void* X; const void* W;
  const float *bb, *gg, *bev; void* Y; int i0, isB;
  if (bx < nbxA) { X = XA; W = WA; bb = bA; gg = gA; bev = beA; Y = YA; i0 = bx * 32; isB = 0; }
  else           { X = XB; W = WB; bb = bB; gg = gB; bev = beB; Y = YB; i0 = (bx - nbxA) * 32; isB = 1; }
  const int j0 = by * 32;
  const int tid = threadIdx.x, w = tid >> 6, lane = tid & 63, lg = lane >> 4, lr = lane & 15;
  const int mt = w >> 1, ct = w & 1;
  const int row = tid >> 2, k8 = (tid & 3) * 8;

  f32x4 acc = f32x4{0.f, 0.f, 0.f, 0.f};

  ushort8_t sv = (row < 32) ? ld8<XBF>(X, (size_t)(i0 + row) * K + k8)
                            : ld8<WBF>(W, (size_t)(j0 + row - 32) * K + k8);
  for (int kt = 0; kt < K; kt += 32) {
    const int buf = (kt >> 5) & 1;
    if (row < 32) *(ushort8_t*)&Xs[buf][row][k8] = sv;
    else          *(ushort8_t*)&Ws[buf][row - 32][k8] = sv;
    __syncthreads();
    if (kt + 32 < K)
      sv = (row < 32) ? ld8<XBF>(X, (size_t)(i0 + row) * K + kt + 32 + k8)
                      : ld8<WBF>(W, (size_t)(j0 + row - 32) * K + kt + 32 + k8);
    bf16x8 af = *(const bf16x8*)&Xs[buf][mt * 16 + lr][lg * 8];
    bf16x8 bf_ = *(const bf16x8*)&Ws[buf][ct * 16 + lr][lg * 8];
    acc = __builtin_amdgcn_mfma_f32_16x16x32_bf16(af, bf_, acc, 0, 0, 0);
  }
  const int c = j0 + ct * 16 + lr;
  const float g = gg[c], bv = bb[c], ev = bev[c];
  #pragma unroll
  for (int r = 0; r < 4; ++r) {
    const int rowo = i0 + mt * 16 + 4 * lg + r;
    float t = fmaxf(g * (acc[r] + bv) + ev, 0.f);
    if (OUT_BF16) ((ushort_t*)Y)[(size_t)rowo * J + c] = f2b(t);
    else {
      ((float*)Y)[(size_t)rowo * J + c] = t;
      if (isB && YBTb) YBTb[(size_t)c * 128 + rowo] = f2b(t);
    }
  }
}

// ---------- proj (R13, unchanged) ----------
__global__ __launch_bounds__(256) void proj32(
    const float* __restrict__ Aenc, const float* __restrict__ Benc,
    const float* __restrict__ mw1, const float* __restrict__ mb1,
    const float* __restrict__ mg1, const float* __restrict__ mbe1,
    float* __restrict__ PA2, float* __restrict__ PB2, int nbxA,
    const float* __restrict__ mw2, const float* __restrict__ mw3,
    ushort_t* __restrict__ mw2b, ushort_t* __restrict__ mw3b)
{
  __shared__ float ps[4][32];
  const int tid = threadIdx.x, bx = blockIdx.x;
  if (bx >= nbxA + 32) {
    const int g = (bx - nbxA - 32) * 256 + tid;
    const float* s; ushort_t* d; int j;
    if (g < 256) { s = mw2; d = mw2b; j = g; }
    else         { s = mw3; d = mw3b; j = g - 256; }
    float4_t v0 = *(const float4_t*)&s[(size_t)j * 8];
    float4_t v1 = *(const float4_t*)&s[(size_t)j * 8 + 4];
    ushort8_t u;
    #pragma unroll
    for (int e = 0; e < 4; ++e) { u[e] = f2b(v0[e]); u[4 + e] = f2b(v1[e]); }
    *(ushort8_t*)&d[(size_t)j * 8] = u;
    return;
  }
  const float* X; float* P; int n0, wb;
  if (bx < nbxA) { X = Aenc; P = PA2; n0 = bx * 4; wb = 1; }
  else           { X = Benc; P = PB2; n0 = (bx - nbxA) * 4; wb = 0; }
  const int k = tid & 31, r = (tid >> 5) & 3, half = tid >> 7;
  const int n = n0 + r;
  const float* xp = &X[(size_t)n * 256 + half * 128];
  const float* wp = &mw1[k * 256 + half * 128];
  float s = 0.f;
  #pragma unroll 8
  for (int q = 0; q < 128; q += 4) {
    float4_t xv = *(const float4_t*)&xp[q];
    float4_t wv = *(const float4_t*)&wp[q];
    #pragma unroll
    for (int e = 0; e < 4; ++e) s = fmaf(xv[e], wv[e], s);
  }
  if (half == 1) ps[r][k] = s;
  __syncthreads();
  if (half == 0) {
    s += ps[r][k];
    P[(size_t)n * 32 + k] = wb ? (mg1[k] * (s + mb1[k]) + mbe1[k]) : (mg1[k] * s);
  }
}

// ---------- fused main kernel: one wave = one n, zero barriers, A-frags resident ----------
// MFMA 16x16x32_bf16: A frag m=lane&15,k=(lane>>4)*8+e; B frag c=lane&15,same k;
// C/D col=lane&15,row=(lane>>4)*4+reg.
// Phase2: h2 read from LDS ONCE into af0/af1[8] (64 VGPR), reused by all 16 ct.
// Per-wave slab: h2[128][72] bf16 + att[256] f32 = 19456B; 4 waves/block = 77824B.
__global__ __launch_bounds__(256, 2) void main_attn(
    const float* __restrict__ PA2, const float* __restrict__ PB2,
    const float* __restrict__ A, const ushort_t* __restrict__ BmTb,
    const ushort_t* __restrict__ mw2b, const float* __restrict__ mb2,
    const float* __restrict__ mg2, const float* __restrict__ mbe2,
    const ushort_t* __restrict__ mw3b, const float* __restrict__ mb3,
    const float* __restrict__ mg3, const float* __restrict__ mbe3,
    const float* __restrict__ fcw, const float* __restrict__ fcb,
    float* __restrict__ outp)
{
  __shared__ __align__(16) char smem[77824];
  const int tid = threadIdx.x;
  const int w = tid >> 6, lane = tid & 63, lg = lane >> 4, lr = lane & 15;
  const int n = blockIdx.x * 4 + w;
  ushort_t* h2s = (ushort_t*)(smem + w * 19456);
  float* attL   = (float*)(smem + w * 19456 + 18432);
  const float LOG2E = 1.4426950408889634f;

  // ---- phase1: h2[m][j] = relu(g2*(relu(PA2[n]-PB2[m]) @ mw2^T + b2) + be2) ----
  {
    bf16x8 b1[4];
    float g2h[4], b2h[4], e2h[4];
    #pragma unroll
    for (int jt = 0; jt < 4; ++jt) {
      b1[jt] = *(const bf16x8*)&mw2b[(jt * 16 + lr) * 32 + lg * 8];
      const int j = jt * 16 + lr;
      g2h[jt] = mg2[j]; b2h[jt] = mb2[j]; e2h[jt] = mbe2[j];
    }
    const float* pa = &PA2[(size_t)n * 32 + lg * 8];
    float4_t pa0 = *(const float4_t*)pa;
    float4_t pa1 = *(const float4_t*)(pa + 4);
    #pragma unroll
    for (int mt = 0; mt < 8; ++mt) {
      const float* pb = &PB2[(size_t)(mt * 16 + lr) * 32 + lg * 8];
      float4_t pb0 = *(const float4_t*)pb;
      float4_t pb1 = *(const float4_t*)(pb + 4);
      bf16x8 a1;
      #pragma unroll
      for (int e = 0; e < 4; ++e) {
        a1[e]     = (short)f2b(fmaxf(pa0[e] - pb0[e], 0.f));
        a1[4 + e] = (short)f2b(fmaxf(pa1[e] - pb1[e], 0.f));
      }
      f32x4 acc1[4];
      #pragma unroll
      for (int jt = 0; jt < 4; ++jt) acc1[jt] = f32x4{0.f, 0.f, 0.f, 0.f};
      #pragma unroll
      for (int jt = 0; jt < 4; ++jt)
        acc1[jt] = __builtin_amdgcn_mfma_f32_16x16x32_bf16(a1, b1[jt], acc1[jt], 0, 0, 0);
      #pragma unroll
      for (int jt = 0; jt < 4; ++jt)
        #pragma unroll
        for (int r = 0; r < 4; ++r)
          h2s[(mt * 16 + 4 * lg + r) * 72 + jt * 16 + lr] =
              f2b(fmaxf(g2h[jt] * (acc1[jt][r] + b2h[jt]) + e2h[jt], 0.f));
    }
  }
  // intra-wave ordering: compiler lgkmcnt; no barrier.

  // ---- load ALL phase2 A-frags once: 16 ds_read_b128 -> 64 VGPR, reused 16x ----
  bf16x8 af0[8], af1[8];
  #pragma unroll
  for (int mt = 0; mt < 8; ++mt) {
    af0[mt] = *(const bf16x8*)&h2s[(mt * 16 + lr) * 72 + lg * 8];
    af1[mt] = *(const bf16x8*)&h2s[(mt * 16 + lr) * 72 + 32 + lg * 8];
  }

  // ---- phase2 + softmax: 16 ct-iterations, MFMA from registers ----
  #pragma unroll 4
  for (int ct = 0; ct < 16; ++ct) {
    const int c = ct * 16 + lr;
    bf16x8 bfr0 = *(const bf16x8*)&mw3b[(size_t)c * 64 + lg * 8];
    bf16x8 bfr1 = *(const bf16x8*)&mw3b[(size_t)c * 64 + 32 + lg * 8];
    f32x4 acc[8];
    #pragma unroll
    for (int mt = 0; mt < 8; ++mt) acc[mt] = f32x4{0.f, 0.f, 0.f, 0.f};
    #pragma unroll
    for (int mt = 0; mt < 8; ++mt) {
      acc[mt] = __builtin_amdgcn_mfma_f32_16x16x32_bf16(af0[mt], bfr0, acc[mt], 0, 0, 0);
      acc[mt] = __builtin_amdgcn_mfma_f32_16x16x32_bf16(af1[mt], bfr1, acc[mt], 0, 0, 0);
    }
    const float g = mg3[c];
    const float gs = g * LOG2E;
    const float cs = (g * mb3[c] + mbe3[c]) * LOG2E;
    f32x4 sm4 = f32x4{0.f, 0.f, 0.f, 0.f};
    f32x4 wb4 = f32x4{0.f, 0.f, 0.f, 0.f};
    #pragma unroll
    for (int mt = 0; mt < 8; ++mt) {
      ushort4_t bv4 = *(const ushort4_t*)&BmTb[(size_t)c * 128 + mt * 16 + 4 * lg];
      #pragma unroll
      for (int r = 0; r < 4; ++r) {
        float t = fmaf(gs, acc[mt][r], cs);
        float p = __builtin_amdgcn_exp2f(__builtin_amdgcn_fmed3f(t, 0.f, 80.f));
        sm4[r] += p;
        wb4[r] = fmaf(p, b2f(bv4[r]), wb4[r]);
      }
    }
    float sm = (sm4[0] + sm4[1]) + (sm4[2] + sm4[3]);
    float wb = (wb4[0] + wb4[1]) + (wb4[2] + wb4[3]);
    sm += __shfl_xor(sm, 16, 64);  wb += __shfl_xor(wb, 16, 64);
    sm += __shfl_xor(sm, 32, 64);  wb += __shfl_xor(wb, 32, 64);
    if (lg == 0)
      attL[c] = A[(size_t)n * 256 + c] - wb / sm;
  }

  // ---- fc (intra-wave): lane covers c = lane*4..lane*4+3 ----
  {
    float4_t av = *(const float4_t*)&attL[lane * 4];
    #pragma unroll
    for (int o = 0; o < 13; ++o) {
      float4_t wv = *(const float4_t*)&fcw[(size_t)o * 256 + lane * 4];
      float s = av[0] * wv[0];
      s = fmaf(av[1], wv[1], s);
      s = fmaf(av[2], wv[2], s);
      s = fmaf(av[3], wv[3], s);
      #pragma unroll
      for (int st = 1; st <= 32; st <<= 1) s += __shfl_xor(s, st, 64);
      if (lane == 0) outp[(size_t)n * 13 + o] = s + fcb[o];
    }
  }
}

extern "C" void kernel_launch(void* const* d_in, const int* in_sizes, int n_in,
                              void* d_out, int out_size, void* d_ws, size_t ws_size,
                              hipStream_t stream)
{
  const float* ext = (const float*)d_in[0];
  const float* lab = (const float*)d_in[1];
  const float* w1a = (const float*)d_in[2];
  const float* b1a = (const float*)d_in[3];
  const float* g1a = (const float*)d_in[4];
  const float* be1a= (const float*)d_in[5];
  const float* w1b = (const float*)d_in[6];
  const float* b1b = (const float*)d_in[7];
  const float* g1b = (const float*)d_in[8];
  const float* be1b= (const float*)d_in[9];
  const float* w2a = (const float*)d_in[10];
  const float* b2a = (const float*)d_in[11];
  const float* g2a = (const float*)d_in[12];
  const float* be2a= (const float*)d_in[13];
  const float* w2b = (const float*)d_in[14];
  const float* b2b = (const float*)d_in[15];
  const float* g2b = (const float*)d_in[16];
  const float* be2b= (const float*)d_in[17];
  const float* mw1 = (const float*)d_in[18];
  const float* mb1 = (const float*)d_in[19];
  const float* mg1 = (const float*)d_in[20];
  const float* mbe1= (const float*)d_in[21];
  const float* mw2 = (const float*)d_in[22];
  const float* mb2 = (const float*)d_in[23];
  const float* mg2 = (const float*)d_in[24];
  const float* mbe2= (const float*)d_in[25];
  const float* mw3 = (const float*)d_in[26];
  const float* mb3 = (const float*)d_in[27];
  const float* mg3 = (const float*)d_in[28];
  const float* mbe3= (const float*)d_in[29];
  const float* fcw = (const float*)d_in[30];
  const float* fcb = (const float*)d_in[31];

  char* ws = (char*)d_ws;
  ushort_t* Y1ab = (ushort_t*)(ws);                       // [0,2M) bf16 (dead after enc2)
  float*    PA2  = (float*)(ws);                          // [0,256K) written by proj
  float*    PB2  = (float*)(ws + 262144);                 // [256K,272K)
  float*    Aenc = (float*)(ws + (2u << 20));             // [2M,4M)
  char* b5 = ws + (4u << 20);
  ushort_t* mw2b  = (ushort_t*)(b5);                      // 64x32 bf16
  ushort_t* mw3b  = (ushort_t*)(b5 + 4096);               // 256x64 bf16
  ushort_t* Y1bb  = (ushort_t*)(b5 + 36864);              // 128x512 bf16
  float*    Benc  = (float*)(b5 + 167936);                // 128x256 f32
  ushort_t* BencTb= (ushort_t*)(b5 + 299008);             // 256x128 bf16 (64KB)

  enc_mfma<0, 0, 1><<<dim3(68, 16), 256, 0, stream>>>(
      (const void*)ext, (const void*)w1a, b1a, g1a, be1a, (void*)Y1ab,
      (const void*)lab, (const void*)w2a, b2a, g2a, be2a, (void*)Y1bb,
      (ushort_t*)nullptr, 512, 352, 64);
  enc_mfma<1, 0, 0><<<dim3(68, 8), 256, 0, stream>>>(
      (const void*)Y1ab, (const void*)w1b, b1b, g1b, be1b, (void*)Aenc,
      (const void*)Y1bb, (const void*)w2b, b2b, g2b, be2b, (void*)Benc,
      BencTb, 256, 512, 64);
  proj32<<<553, 256, 0, stream>>>(Aenc, Benc, mw1, mb1, mg1, mbe1, PA2, PB2, 512,
                                  mw2, mw3, mw2b, mw3b);
  main_attn<<<512, 256, 0, stream>>>(PA2, PB2, Aenc, BencTb,
                                     mw2b, mb2, mg2, mbe2, mw3b, mb3, mg3, mbe3,
                                     fcw, fcb, (float*)d_out);
}